// Round 12
// baseline (159.578 us; speedup 1.0000x reference)
//
#include <hip/hip_runtime.h>
#include <hip/hip_bf16.h>

#define SEQ 2048
#define DIMM 2048
#define NQH 32
#define NKVH 8
#define HD 64

typedef _Float16 half8 __attribute__((ext_vector_type(8)));
typedef float f32x4 __attribute__((ext_vector_type(4)));
using fp16 = _Float16;

typedef __attribute__((address_space(1))) unsigned int ga_u32;
typedef __attribute__((address_space(3))) unsigned int ls_u32;

__device__ __forceinline__ void gll16(const void* g, void* l) {
    __builtin_amdgcn_global_load_lds((const ga_u32*)g, (ls_u32*)l, 16, 0, 0);
}

// ---------------- cast fp32 -> fp16 (vectorized) ----------------
__global__ void cast_f32_f16(const float* __restrict__ in, fp16* __restrict__ out, int n) {
    int i = (blockIdx.x * 256 + threadIdx.x) * 4;
    if (i < n) {
        float4 v = *reinterpret_cast<const float4*>(in + i);
#pragma unroll
        for (int j = 0; j < 4; j++) out[i + j] = (fp16)(&v.x)[j];
    }
}

// ------------- fused weight transpose: wq/wk/wv fp32 [head][2048][64] -> wqkvt fp16 [48][64][2048] -------------
__global__ void transpose_qkvw(const float* __restrict__ wq, const float* __restrict__ wk,
                               const float* __restrict__ wv, fp16* __restrict__ out) {
    __shared__ float tile[64][65];
    const int z = blockIdx.z;
    const float* inh = (z < 32) ? wq + (size_t)z * SEQ * HD
                                : (z < 40) ? wk + (size_t)(z - 32) * SEQ * HD
                                           : wv + (size_t)(z - 40) * SEQ * HD;
    fp16* outh = out + (size_t)z * HD * SEQ;
    int r0 = blockIdx.x * 64;
    int t = threadIdx.x;
#pragma unroll
    for (int i = 0; i < 16; i++) {
        int idx = i * 256 + t;
        int r = idx >> 6, c = idx & 63;
        tile[r][c] = inh[(size_t)(r0 + r) * HD + c];
    }
    __syncthreads();
#pragma unroll
    for (int i = 0; i < 16; i++) {
        int idx = i * 256 + t;
        int cc = idx >> 6, rr = idx & 63;
        outh[(size_t)cc * SEQ + r0 + rr] = (fp16)tile[rr][cc];
    }
}

// ------------- tiled transpose + cast: in fp32 [R][C] -> out fp16 [C][R] (for w_out) -------------
__global__ void transpose_cast(const float* __restrict__ in, fp16* __restrict__ out, int R, int C) {
    __shared__ float tile[64][65];
    int r0 = blockIdx.x * 64, c0 = blockIdx.y * 64;
    int t = threadIdx.x;
#pragma unroll
    for (int i = 0; i < 16; i++) {
        int idx = i * 256 + t;
        int r = idx >> 6, c = idx & 63;
        tile[r][c] = in[(size_t)(r0 + r) * C + c0 + c];
    }
    __syncthreads();
#pragma unroll
    for (int i = 0; i < 16; i++) {
        int idx = i * 256 + t;
        int cc = idx >> 6, rr = idx & 63;
        out[(size_t)(c0 + cc) * R + r0 + rr] = (fp16)tile[rr][cc];
    }
}

// ---------------- fused RoPE + V-transpose (both read proj[2048][3072]) ----------------
// blocks [0, 10240): RoPE on q/k heads; blocks [10240, 10496): V transpose.
__global__ void rope_vt_kernel(const fp16* __restrict__ proj, fp16* __restrict__ qb,
                               fp16* __restrict__ kb, fp16* __restrict__ vtb) {
    __shared__ fp16 tile[64][72];
    const int bx = blockIdx.x;
    if (bx < 10240) {
        int tid = bx * 256 + threadIdx.x;  // 40*2048*32
        int pair = tid & 31;
        int s = (tid >> 5) & 2047;
        int head = tid >> 16;
        const fp16* src = proj + (size_t)s * 3072 + head * HD + 2 * pair;
        float x1 = (float)src[0];
        float x2 = (float)src[1];
        float invf = expf(-((float)pair / 32.0f) * 9.210340371976184f);  // 10000^(-2j/64)
        float ang = (float)s * invf;
        float sn, cs;
        sincosf(ang, &sn, &cs);
        float o1 = cs * x1 - sn * x2;
        float o2 = sn * x1 + cs * x2;
        fp16* dst = (head < NQH) ? (qb + ((size_t)head * SEQ + s) * HD + 2 * pair)
                                 : (kb + ((size_t)(head - NQH) * SEQ + s) * HD + 2 * pair);
        dst[0] = (fp16)o1;
        dst[1] = (fp16)o2;
    } else {
        const int idx = bx - 10240;          // 0..255
        const int g = idx >> 5;              // kv group
        const int s0 = (idx & 31) * 64;      // seq tile
        const int t = threadIdx.x;
#pragma unroll
        for (int i = 0; i < 16; i++) {
            int id2 = i * 256 + t;
            int r = id2 >> 6, c = id2 & 63;
            tile[r][c] = proj[(size_t)(s0 + r) * 3072 + 2560 + g * HD + c];
        }
        __syncthreads();
#pragma unroll
        for (int i = 0; i < 16; i++) {
            int id2 = i * 256 + t;
            int cc = id2 >> 6, rr = id2 & 63;
            vtb[((size_t)g * HD + cc) * SEQ + s0 + rr] = tile[rr][cc];
        }
    }
}

// ============ GEMM core: 128x128 tile, BK=64, DOUBLE-BUFFERED gll staging, XOR swizzle ============
#define GEMM_CORE(A_, Bt_, K_)                                                              \
    __shared__ fp16 As[2][128][64];                                                         \
    __shared__ fp16 Bs[2][128][64];                                                         \
    const int t = threadIdx.x;                                                              \
    const int m0 = blockIdx.x * 128, n0 = blockIdx.y * 128;                                 \
    const int wid = t >> 6, lane = t & 63;                                                  \
    const int wm = (wid >> 1) * 64, wn = (wid & 1) * 64;                                    \
    const int lr = lane & 15, lg = lane >> 4;                                               \
    f32x4 acc[4][4] = {};                                                                   \
    const int nk = (K_) >> 6;                                                               \
    auto stage_ = [&](int kt, int b) {                                                      \
        _Pragma("unroll") for (int i = 0; i < 4; i++) {                                     \
            int s = i * 256 + t;                                                            \
            int row = s >> 3, ch = s & 7;                                                   \
            int lch = ch ^ (row & 7); /* pre-swizzled global source, linear LDS dest */     \
            gll16((A_) + (size_t)(m0 + row) * (K_) + (kt << 6) + lch * 8,                   \
                  (char*)&As[b][0][0] + s * 16);                                            \
            gll16((Bt_) + (size_t)(n0 + row) * (K_) + (kt << 6) + lch * 8,                  \
                  (char*)&Bs[b][0][0] + s * 16);                                            \
        }                                                                                   \
    };                                                                                      \
    stage_(0, 0);                                                                           \
    __syncthreads();                                                                        \
    for (int kt = 0; kt < nk; ++kt) {                                                       \
        const int cur = kt & 1;                                                             \
        if (kt + 1 < nk) stage_(kt + 1, cur ^ 1);                                           \
        _Pragma("unroll") for (int kk = 0; kk < 2; kk++) {                                  \
            half8 af[4], bfv[4];                                                            \
            _Pragma("unroll") for (int m = 0; m < 4; m++) {                                 \
                int row = wm + m * 16 + lr;                                                 \
                af[m] = *(const half8*)((const char*)&As[cur][row][0] + (((kk * 4 + lg) ^ (row & 7)) * 16)); \
            }                                                                               \
            _Pragma("unroll") for (int n = 0; n < 4; n++) {                                 \
                int row = wn + n * 16 + lr;                                                 \
                bfv[n] = *(const half8*)((const char*)&Bs[cur][row][0] + (((kk * 4 + lg) ^ (row & 7)) * 16)); \
            }                                                                               \
            __builtin_amdgcn_s_setprio(1);                                                  \
            _Pragma("unroll") for (int m = 0; m < 4; m++)                                   \
                _Pragma("unroll") for (int n = 0; n < 4; n++)                               \
                    acc[m][n] = __builtin_amdgcn_mfma_f32_16x16x32_f16(af[m], bfv[n], acc[m][n], 0, 0, 0); \
            __builtin_amdgcn_s_setprio(0);                                                  \
        }                                                                                   \
        __syncthreads(); /* vmcnt drained here -> next tile ready; protects buf reuse */    \
    }

// ---------------- QKV projection: proj[2048][3072] fp16, trivial epilogue ----------------
__global__ __launch_bounds__(256) void gemm_proj(
    const fp16* __restrict__ A, const fp16* __restrict__ Bt, fp16* __restrict__ Cout) {
    GEMM_CORE(A, Bt, 2048)
#pragma unroll
    for (int m = 0; m < 4; m++)
#pragma unroll
        for (int n = 0; n < 4; n++)
#pragma unroll
            for (int r = 0; r < 4; r++) {
                int row = m0 + wm + m * 16 + lg * 4 + r;
                int col = n0 + wn + n * 16 + lr;
                Cout[(size_t)row * 3072 + col] = (fp16)acc[m][n][r];
            }
}

// ---------------- out projection: C[2048][2048] fp32 ----------------
__global__ __launch_bounds__(256) void gemm_out2(
    const fp16* __restrict__ A, const fp16* __restrict__ Bt, float* __restrict__ Cout) {
    GEMM_CORE(A, Bt, 2048)
#pragma unroll
    for (int m = 0; m < 4; m++)
#pragma unroll
        for (int n = 0; n < 4; n++)
#pragma unroll
            for (int r = 0; r < 4; r++) {
                int row = m0 + wm + m * 16 + lg * 4 + r;
                int col = n0 + wn + n * 16 + lr;
                Cout[(size_t)row * 2048 + col] = acc[m][n][r];
            }
}

// ---------------- causal flash attention (40960B LDS -> 4 blocks/CU; balanced qt map) ----------------
// grid (1024): head = bx & 31; grp = bx>>5; a = grp&7, sel = grp>>3:
//   qt = {31-a, 8+a, 23-a, a}[sel]  — bijective over 0..31; each quadruple sums to 62
//   (66 tile-iters per 4 blocks), so stride-256 round-robin placement is statically balanced.
__global__ __launch_bounds__(256) void attn_kernel(
    const fp16* __restrict__ qb, const fp16* __restrict__ kb,
    const fp16* __restrict__ vt, fp16* __restrict__ o_all) {
    __shared__ fp16 Kb[2][64][64];  // 16 KB [buf][kv row][dim]   (16B-chunk XOR swizzled)
    __shared__ fp16 Vb[2][64][64];  // 16 KB [buf][dim][kv-local] (swizzled)
    __shared__ fp16 P[4][16][64];   //  8 KB swizzled stride-64 => total 40960 B = 4 blocks/CU
    const int t = threadIdx.x, wid = t >> 6, lane = t & 63;
    const int bx = blockIdx.x;
    const int grp = bx >> 5;  // 0..31
    const int a = grp & 7;
    const int sel = grp >> 3;
    const int qt = (sel == 0) ? (31 - a) : (sel == 1) ? (8 + a) : (sel == 2) ? (23 - a) : a;
    const int head = bx & 31;
    const int g = head >> 2;
    const int lr = lane & 15, lg = lane >> 4;
    const fp16* qh = qb + (size_t)head * SEQ * HD;
    const fp16* kh = kb + (size_t)g * SEQ * HD;
    const fp16* vh = vt + (size_t)g * HD * SEQ;
    const int srow = lane >> 3;   // 0..7
    const int schunk = lane & 7;  // 16B chunk 0..7
    const int qr0 = qt * 64 + wid * 16;

    half8 aq0 = *reinterpret_cast<const half8*>(qh + (size_t)(qr0 + lr) * HD + lg * 8);
    half8 aq1 = *reinterpret_cast<const half8*>(qh + (size_t)(qr0 + lr) * HD + 32 + lg * 8);
#pragma unroll
    for (int e = 0; e < 8; e++) {  // fold 1/8 score scale into Q (exact: pow2)
        aq0[e] *= (fp16)0.125f;
        aq1[e] *= (fp16)0.125f;
    }
    f32x4 o[4] = {};
    float m[4], lsum[4];  // lsum lane-partial until the end
#pragma unroll
    for (int r = 0; r < 4; r++) { m[r] = -1e30f; lsum[r] = 0.0f; }
    const int nt = qt + 1;

    auto stage = [&](int kt, int b) {
        const int kv0 = kt << 6;
#pragma unroll
        for (int i = 0; i < 2; ++i) {
            int row = wid * 16 + i * 8 + srow;
            int sw = (schunk ^ srow) * 8;
            gll16(kh + (size_t)(kv0 + row) * HD + sw, &Kb[b][wid * 16 + i * 8][0]);
            gll16(vh + (size_t)row * SEQ + kv0 + sw, &Vb[b][wid * 16 + i * 8][0]);
        }
    };

    stage(0, 0);
    __syncthreads();
    for (int tt = 0; tt < nt; ++tt) {
        const int cur = tt & 1;
        if (tt + 1 < nt) stage(tt + 1, cur ^ 1);
        const int kv0 = tt << 6;
        f32x4 sc[4];
        __builtin_amdgcn_s_setprio(1);
#pragma unroll
        for (int f = 0; f < 4; ++f) {
            int row = f * 16 + lr;
            const char* kbp = (const char*)&Kb[cur][row][0];
            half8 b0 = *(const half8*)(kbp + (((lg) ^ (row & 7)) * 16));
            half8 b1 = *(const half8*)(kbp + (((4 + lg) ^ (row & 7)) * 16));
            f32x4 s = {};
            s = __builtin_amdgcn_mfma_f32_16x16x32_f16(aq0, b0, s, 0, 0, 0);
            s = __builtin_amdgcn_mfma_f32_16x16x32_f16(aq1, b1, s, 0, 0, 0);
            sc[f] = s;
        }
        __builtin_amdgcn_s_setprio(0);
        if (tt == qt) {
#pragma unroll
            for (int f = 0; f < 4; f++)
#pragma unroll
                for (int r = 0; r < 4; r++) {
                    int q = qr0 + lg * 4 + r, kv = kv0 + f * 16 + lr;
                    if (kv > q) sc[f][r] = -1e30f;
                }
        }
        // ---- defer-max: lane-local check; rescale only if some row grew past m+8 ----
        float lmax[4];
        bool ok = true;
#pragma unroll
        for (int r = 0; r < 4; r++) {
            lmax[r] = fmaxf(fmaxf(sc[0][r], sc[1][r]), fmaxf(sc[2][r], sc[3][r]));
            ok = ok && (lmax[r] <= m[r] + 8.0f);
        }
        if (!__all(ok)) {  // rare path: full cross-lane max + rescale
#pragma unroll
            for (int r = 0; r < 4; r++) {
                float v = lmax[r];
                v = fmaxf(v, __shfl_xor(v, 1));
                v = fmaxf(v, __shfl_xor(v, 2));
                v = fmaxf(v, __shfl_xor(v, 4));
                v = fmaxf(v, __shfl_xor(v, 8));
                float mn = fmaxf(m[r], v);
                float alpha = __expf(m[r] - mn);
                m[r] = mn;
                lsum[r] *= alpha;
#pragma unroll
                for (int vf = 0; vf < 4; vf++) o[vf][r] *= alpha;
            }
        }
#pragma unroll
        for (int f = 0; f < 4; f++)
#pragma unroll
            for (int r = 0; r < 4; r++) {
                float p = __expf(sc[f][r] - m[r]);  // bounded by e^8
                sc[f][r] = p;
                lsum[r] += p;  // lane-partial; reduced once at the end
            }
        // P write: stride-64 rows, 16B-chunk XOR swizzle (chunk ^= row&7)
        {
            char* pb = (char*)&P[wid][0][0];
#pragma unroll
            for (int f = 0; f < 4; f++)
#pragma unroll
                for (int r = 0; r < 4; r++) {
                    int row = lg * 4 + r, col = f * 16 + lr;
                    *(fp16*)(pb + row * 128 + (((col >> 3) ^ (row & 7)) * 16) + (col & 7) * 2) =
                        (fp16)sc[f][r];
                }
        }
        __builtin_amdgcn_s_setprio(1);
#pragma unroll
        for (int half = 0; half < 2; half++) {
            const char* pb = (const char*)&P[wid][0][0];
            half8 pa = *(const half8*)(pb + lr * 128 + (((half * 4 + lg) ^ (lr & 7)) * 16));
#pragma unroll
            for (int vf = 0; vf < 4; vf++) {
                int d = vf * 16 + lr;
                int xo = ((half * 4 + lg) ^ (d & 7)) * 16;
                half8 bv = *(const half8*)((const char*)&Vb[cur][d][0] + xo);
                o[vf] = __builtin_amdgcn_mfma_f32_16x16x32_f16(pa, bv, o[vf], 0, 0, 0);
            }
        }
        __builtin_amdgcn_s_setprio(0);
        __syncthreads();  // drains vmcnt (stage of tt+1) + protects buffer reuse
    }
    // final row-sum reduce (once)
#pragma unroll
    for (int r = 0; r < 4; r++) {
        float v = lsum[r];
        v += __shfl_xor(v, 1);
        v += __shfl_xor(v, 2);
        v += __shfl_xor(v, 4);
        v += __shfl_xor(v, 8);
        lsum[r] = v;
    }
#pragma unroll
    for (int vf = 0; vf < 4; vf++)
#pragma unroll
        for (int r = 0; r < 4; r++) {
            float v = o[vf][r] / lsum[r];
            o_all[(size_t)(qr0 + lg * 4 + r) * 2048 + head * 64 + vf * 16 + lr] = (fp16)v;
        }
}

extern "C" void kernel_launch(void* const* d_in, const int* in_sizes, int n_in,
                              void* d_out, int out_size, void* d_ws, size_t ws_size,
                              hipStream_t stream) {
    const float* x  = (const float*)d_in[0];
    const float* wq = (const float*)d_in[1];
    const float* wk = (const float*)d_in[2];
    const float* wv = (const float*)d_in[3];
    const float* wo = (const float*)d_in[4];
    float* out = (float*)d_out;
    char* ws = (char*)d_ws;

    // Workspace (44 MB peak). Aliases: w2t reuses xh (dead after gemm_proj);
    // o_all reuses proj (dead after rope_vt).
    fp16* xh    = (fp16*)(ws);                        // 8 MB [2048][2048]
    fp16* w2t   = xh;                                 // alias
    fp16* wqkvt = (fp16*)(ws + ((size_t)8 << 20));    // 12 MB [3072][2048] ([48][64][2048])
    fp16* proj  = (fp16*)(ws + ((size_t)20 << 20));   // 12 MB [2048][3072]
    fp16* o_all = proj;                               // alias (8 MB)
    fp16* qbuf  = (fp16*)(ws + ((size_t)32 << 20));   // 8 MB [32][2048][64]
    fp16* kbuf  = (fp16*)(ws + ((size_t)40 << 20));   // 2 MB [8][2048][64]
    fp16* vtb   = (fp16*)(ws + ((size_t)42 << 20));   // 2 MB [8][64][2048]

    cast_f32_f16<<<dim3(4096), 256, 0, stream>>>(x, xh, SEQ * DIMM);
    transpose_qkvw<<<dim3(32, 1, 48), 256, 0, stream>>>(wq, wk, wv, wqkvt);
    gemm_proj<<<dim3(16, 24), 256, 0, stream>>>(xh, wqkvt, proj);
    rope_vt_kernel<<<dim3(10496), 256, 0, stream>>>(proj, qbuf, kbuf, vtb);
    transpose_cast<<<dim3(32, 32), 256, 0, stream>>>(wo, w2t, 2048, 2048);
    attn_kernel<<<dim3(1024), 256, 0, stream>>>(qbuf, kbuf, vtb, o_all);
    gemm_out2<<<dim3(16, 16), 256, 0, stream>>>(o_all, w2t, out);
}